// Round 1
// baseline (1586.085 us; speedup 1.0000x reference)
//
#include <hip/hip_runtime.h>
#include <hip/hip_bf16.h>

#define N_FEAT 128
#define K_DIM 512

typedef __attribute__((ext_vector_type(8))) short short8;
typedef __attribute__((ext_vector_type(4))) float f32x4;

static __device__ __forceinline__ short f2bf(float f) {
    // round-to-nearest-even f32 -> bf16 (inputs are finite normals)
    unsigned u = __float_as_uint(f);
    unsigned r = (u + 0x7FFFu + ((u >> 16) & 1u)) >> 16;
    return (short)r;
}

// ---------------------------------------------------------------------------
// dtype detection: reference says int64 indices; harness *may* hand us int32.
// Sample 512 values as int64; any out of [0,n) => int32. (If data is int32,
// an int64 view has a ~random high word >= 2^32 with overwhelming odds.)
__global__ void k_detect(const long long* __restrict__ e, long long nmax, int* flag) {
    __shared__ int ok;
    if (threadIdx.x == 0) ok = 1;
    __syncthreads();
    long long v = e[threadIdx.x];
    if (v < 0 || v >= nmax) ok = 0;  // benign race
    __syncthreads();
    if (threadIdx.x == 0) *flag = ok;
}

static __device__ __forceinline__ int load_idx(const void* e, int i, int is64) {
    return is64 ? (int)((const long long*)e)[i] : ((const int*)e)[i];
}

// ---------------------------------------------------------------------------
// W [512][128] f32 -> Wt [128][512] bf16 (transposed for K-contiguous frags)
__global__ void k_wt(const float* __restrict__ W, short* __restrict__ Wt) {
    int i = blockIdx.x * 256 + threadIdx.x;  // 65536
    int k = i >> 7, c = i & 127;
    Wt[c * K_DIM + k] = f2bf(W[i]);
}

__global__ void k_deginit(float* __restrict__ deg, int n) {
    int i = blockIdx.x * 256 + threadIdx.x;
    if (i < n) deg[i] = 1.0f;  // self-loop
}

__global__ void k_degedge(const void* __restrict__ eidx, const int* __restrict__ flagp,
                          int E, float* __restrict__ deg) {
    int i = blockIdx.x * 256 + threadIdx.x;
    if (i >= E) return;
    int is64 = *flagp;
    int dst = load_idx(eidx, E + i, is64);
    atomicAdd(&deg[dst], 1.0f);
}

__global__ void k_rsqrt(float* __restrict__ deg, int n) {
    int i = blockIdx.x * 256 + threadIdx.x;
    if (i < n) deg[i] = rsqrtf(deg[i]);
}

// ---------------------------------------------------------------------------
// h = x @ W via bf16 MFMA; epilogue writes h (f32) and d_out = h*dinv^2
// (self-loop term), which also fully initializes poisoned d_out.
#define BM 64
#define BK 32
#define LDP 40  // padded LDS stride (bf16 elems): breaks pow2 bank aliasing

__global__ __launch_bounds__(256) void k_gemm(const float* __restrict__ x,
                                              const short* __restrict__ Wt,
                                              const float* __restrict__ dinv,
                                              float* __restrict__ h,
                                              float* __restrict__ out, int n) {
    __shared__ __align__(16) short As[BM * LDP];
    __shared__ __align__(16) short Bs[N_FEAT * LDP];
    int tid = threadIdx.x;
    int wave = tid >> 6, lane = tid & 63;
    int lr = lane & 15, kg = lane >> 4;
    int row0 = blockIdx.x * BM;

    f32x4 acc[8];
#pragma unroll
    for (int t = 0; t < 8; t++) acc[t] = (f32x4)(0.0f);

    // staging assignments
    int arow = tid >> 2;              // 0..63
    int aq = (tid & 3) * 8;           // 0,8,16,24
    int bcol = tid >> 1;              // 0..127
    int bo = (tid & 1) * 16;          // 0,16

    for (int k0 = 0; k0 < K_DIM; k0 += BK) {
        // stage A tile (f32 global -> bf16 LDS)
        {
            int grow = row0 + arow;
            float4 v0, v1;
            if (grow < n) {
                const float4* p =
                    reinterpret_cast<const float4*>(x + (size_t)grow * K_DIM + k0 + aq);
                v0 = p[0];
                v1 = p[1];
            } else {
                v0 = make_float4(0, 0, 0, 0);
                v1 = v0;
            }
            short* d = &As[arow * LDP + aq];
            d[0] = f2bf(v0.x); d[1] = f2bf(v0.y); d[2] = f2bf(v0.z); d[3] = f2bf(v0.w);
            d[4] = f2bf(v1.x); d[5] = f2bf(v1.y); d[6] = f2bf(v1.z); d[7] = f2bf(v1.w);
        }
        // stage B tile (bf16 global, already transposed: Wt[col][k])
        {
            const float4* pv =
                reinterpret_cast<const float4*>(Wt + bcol * K_DIM + k0 + bo);
            float4 w0 = pv[0];
            float4 w1 = pv[1];
            float4* dv = reinterpret_cast<float4*>(&Bs[bcol * LDP + bo]);
            dv[0] = w0;
            dv[1] = w1;
        }
        __syncthreads();

        // one 16x16x32 MFMA per N-tile; wave owns 16-row strip
        short8 a = *reinterpret_cast<const short8*>(&As[(wave * 16 + lr) * LDP + kg * 8]);
#pragma unroll
        for (int t = 0; t < 8; t++) {
            short8 b = *reinterpret_cast<const short8*>(&Bs[(t * 16 + lr) * LDP + kg * 8]);
            acc[t] = __builtin_amdgcn_mfma_f32_16x16x32_bf16(a, b, acc[t], 0, 0, 0);
        }
        __syncthreads();
    }

    // epilogue: C/D layout row=(lane>>4)*4+r, col=lane&15
    int myrow0 = row0 + wave * 16 + kg * 4;
#pragma unroll
    for (int r = 0; r < 4; r++) {
        int row = myrow0 + r;
        if (row < n) {
            float di = dinv[row];
            float sl = di * di;
#pragma unroll
            for (int t = 0; t < 8; t++) {
                int col = t * 16 + lr;
                float hv = acc[t][r];
                size_t off = (size_t)row * N_FEAT + col;
                h[off] = hv;
                out[off] = hv * sl;
            }
        }
    }
}

// ---------------------------------------------------------------------------
// edge scatter: 32 threads per edge, 4 feats each (float4 gather + 4 atomics)
__global__ __launch_bounds__(256) void k_scatter(const void* __restrict__ eidx,
                                                 const int* __restrict__ flagp, int E,
                                                 const float* __restrict__ dinv,
                                                 const float* __restrict__ h,
                                                 float* __restrict__ out) {
    int tid = blockIdx.x * 256 + threadIdx.x;
    int e = tid >> 5;
    if (e >= E) return;
    int part = tid & 31;
    int is64 = *flagp;
    int src = load_idx(eidx, e, is64);
    int dst = load_idx(eidx, E + e, is64);
    float nrm = dinv[src] * dinv[dst];
    const float4 hv = *reinterpret_cast<const float4*>(h + (size_t)src * N_FEAT + part * 4);
    float* o = out + (size_t)dst * N_FEAT + part * 4;
    atomicAdd(o + 0, hv.x * nrm);
    atomicAdd(o + 1, hv.y * nrm);
    atomicAdd(o + 2, hv.z * nrm);
    atomicAdd(o + 3, hv.w * nrm);
}

// ---------------------------------------------------------------------------
// bias + log_softmax over 128 feats, one wave per node, in-place on d_out
__global__ __launch_bounds__(256) void k_lsm(float* __restrict__ out,
                                             const float* __restrict__ bias, int n) {
    int wave = threadIdx.x >> 6, lane = threadIdx.x & 63;
    int node = blockIdx.x * 4 + wave;
    if (node >= n) return;
    float* p = out + (size_t)node * N_FEAT;
    float v0 = p[lane] + bias[lane];
    float v1 = p[lane + 64] + bias[lane + 64];
    float m = fmaxf(v0, v1);
#pragma unroll
    for (int s = 32; s; s >>= 1) m = fmaxf(m, __shfl_xor(m, s));
    float sum = __expf(v0 - m) + __expf(v1 - m);
#pragma unroll
    for (int s = 32; s; s >>= 1) sum += __shfl_xor(sum, s);
    float lse = m + __logf(sum);
    p[lane] = v0 - lse;
    p[lane + 64] = v1 - lse;
}

// ---------------------------------------------------------------------------
extern "C" void kernel_launch(void* const* d_in, const int* in_sizes, int n_in,
                              void* d_out, int out_size, void* d_ws, size_t ws_size,
                              hipStream_t stream) {
    const float* x = (const float*)d_in[0];
    const void* eidx = d_in[1];
    const float* W = (const float*)d_in[2];
    const float* b = (const float*)d_in[3];
    int n = in_sizes[0] / K_DIM;   // 50000
    int E = in_sizes[1] / 2;       // 800000
    float* out = (float*)d_out;

    char* ws = (char*)d_ws;
    int* flagp = (int*)ws;                       // @0
    float* deg = (float*)(ws + 1024);            // n f32 (becomes dinv in place)
    short* Wt = (short*)(ws + 201728);           // 128*512 bf16 = 128KB
    float* h = (float*)(ws + 332800);            // n*128 f32 = 25.6MB

    k_detect<<<1, 512, 0, stream>>>((const long long*)eidx, (long long)n, flagp);
    k_wt<<<(K_DIM * N_FEAT) / 256, 256, 0, stream>>>(W, Wt);
    k_deginit<<<(n + 255) / 256, 256, 0, stream>>>(deg, n);
    k_degedge<<<(E + 255) / 256, 256, 0, stream>>>(eidx, flagp, E, deg);
    k_rsqrt<<<(n + 255) / 256, 256, 0, stream>>>(deg, n);
    k_gemm<<<(n + BM - 1) / BM, 256, 0, stream>>>(x, Wt, deg, h, out, n);
    k_scatter<<<((size_t)E * 32 + 255) / 256, 256, 0, stream>>>(eidx, flagp, E, deg, h, out);
    k_lsm<<<(n + 3) / 4, 256, 0, stream>>>(out, b, n);
}

// Round 3
// 409.781 us; speedup vs baseline: 3.8706x; 3.8706x over previous
//
#include <hip/hip_runtime.h>
#include <hip/hip_bf16.h>

#define N_FEAT 128
#define K_DIM 512

typedef __attribute__((ext_vector_type(8))) short short8;
typedef __attribute__((ext_vector_type(4))) float f32x4;

static __device__ __forceinline__ short f2bf(float f) {
    unsigned u = __float_as_uint(f);
    unsigned r = (u + 0x7FFFu + ((u >> 16) & 1u)) >> 16;
    return (short)r;
}

// ---------------------------------------------------------------------------
// dtype detection: reference says int64 indices; harness *may* hand us int32.
__global__ void k_detect(const long long* __restrict__ e, long long nmax, int* flag) {
    __shared__ int ok;
    if (threadIdx.x == 0) ok = 1;
    __syncthreads();
    long long v = e[threadIdx.x];
    if (v < 0 || v >= nmax) ok = 0;  // benign race
    __syncthreads();
    if (threadIdx.x == 0) *flag = ok;
}

static __device__ __forceinline__ int load_idx(const void* e, int i, int is64) {
    return is64 ? (int)((const long long*)e)[i] : ((const int*)e)[i];
}

// ---------------------------------------------------------------------------
// W [512][128] f32 -> Wt [128][512] bf16 (transposed: K-contiguous fragments)
__global__ void k_wt(const float* __restrict__ W, short* __restrict__ Wt) {
    int i = blockIdx.x * 256 + threadIdx.x;  // 65536
    int k = i >> 7, c = i & 127;
    Wt[c * K_DIM + k] = f2bf(W[i]);
}

__global__ void k_zero(int* __restrict__ p, int n) {
    int i = blockIdx.x * 256 + threadIdx.x;
    if (i < n) p[i] = 0;
}

// histogram of dst (self-loops NOT counted here; scan adds the +1)
__global__ void k_hist(const void* __restrict__ eidx, const int* __restrict__ flagp,
                       int E, int* __restrict__ cnt) {
    int i = blockIdx.x * 256 + threadIdx.x;
    if (i >= E) return;
    int is64 = *flagp;
    int dst = load_idx(eidx, E + i, is64);
    atomicAdd(&cnt[dst], 1);
}

// single-block exclusive scan of cnt[0..n) -> rowstart & cursor; dinv = rsqrt(1+cnt)
__global__ __launch_bounds__(1024) void k_scan(const int* __restrict__ cnt,
                                               int* __restrict__ rowstart,
                                               int* __restrict__ cursor,
                                               float* __restrict__ dinv, int n) {
    __shared__ int wsum[16];
    __shared__ int carry_s;
    int tid = threadIdx.x, wid = tid >> 6, lane = tid & 63;
    if (tid == 0) carry_s = 0;
    __syncthreads();
    for (int base = 0; base < n; base += 1024) {
        int i = base + tid;
        int v = (i < n) ? cnt[i] : 0;
        if (i < n) dinv[i] = rsqrtf(1.0f + (float)v);
        int x = v;  // inclusive scan within wave
#pragma unroll
        for (int off = 1; off < 64; off <<= 1) {
            int t = __shfl_up(x, off);
            if (lane >= off) x += t;
        }
        if (lane == 63) wsum[wid] = x;
        __syncthreads();
        if (wid == 0 && lane < 16) {
            int s = wsum[lane];
#pragma unroll
            for (int off = 1; off < 16; off <<= 1) {
                int t = __shfl_up(s, off);
                if (lane >= off) s += t;
            }
            wsum[lane] = s;  // inclusive wave sums
        }
        __syncthreads();
        int wexcl = (wid == 0) ? 0 : wsum[wid - 1];
        int excl = carry_s + wexcl + (x - v);
        if (i < n) {
            rowstart[i] = excl;
            cursor[i] = excl;
        }
        int total = wsum[15];
        __syncthreads();
        if (tid == 0) carry_s += total;
        __syncthreads();
    }
    if (threadIdx.x == 0) rowstart[n] = carry_s;
}

// scatter edge ids into CSR slots (int atomics on 200KB cursor array only)
__global__ void k_fill(const void* __restrict__ eidx, const int* __restrict__ flagp,
                       int E, int* __restrict__ cursor, int* __restrict__ col) {
    int e = blockIdx.x * 256 + threadIdx.x;
    if (e >= E) return;
    int is64 = *flagp;
    int src = load_idx(eidx, e, is64);
    int dst = load_idx(eidx, E + e, is64);
    int slot = atomicAdd(&cursor[dst], 1);
    col[slot] = src;
}

// ---------------------------------------------------------------------------
// h = x @ W via bf16 MFMA (writes h only)
#define BM 64
#define BK 32
#define LDP 40  // padded LDS stride (bf16 elems)

__global__ __launch_bounds__(256) void k_gemm(const float* __restrict__ x,
                                              const short* __restrict__ Wt,
                                              float* __restrict__ h, int n) {
    __shared__ __align__(16) short As[BM * LDP];
    __shared__ __align__(16) short Bs[N_FEAT * LDP];
    int tid = threadIdx.x;
    int wave = tid >> 6, lane = tid & 63;
    int lr = lane & 15, kg = lane >> 4;
    int row0 = blockIdx.x * BM;

    f32x4 acc[8];
#pragma unroll
    for (int t = 0; t < 8; t++) acc[t] = (f32x4)(0.0f);

    int arow = tid >> 2;
    int aq = (tid & 3) * 8;
    int bcol = tid >> 1;
    int bo = (tid & 1) * 16;

    for (int k0 = 0; k0 < K_DIM; k0 += BK) {
        {
            int grow = row0 + arow;
            float4 v0, v1;
            if (grow < n) {
                const float4* p =
                    reinterpret_cast<const float4*>(x + (size_t)grow * K_DIM + k0 + aq);
                v0 = p[0];
                v1 = p[1];
            } else {
                v0 = make_float4(0, 0, 0, 0);
                v1 = v0;
            }
            short* d = &As[arow * LDP + aq];
            d[0] = f2bf(v0.x); d[1] = f2bf(v0.y); d[2] = f2bf(v0.z); d[3] = f2bf(v0.w);
            d[4] = f2bf(v1.x); d[5] = f2bf(v1.y); d[6] = f2bf(v1.z); d[7] = f2bf(v1.w);
        }
        {
            const float4* pv =
                reinterpret_cast<const float4*>(Wt + bcol * K_DIM + k0 + bo);
            float4 w0 = pv[0];
            float4 w1 = pv[1];
            float4* dv = reinterpret_cast<float4*>(&Bs[bcol * LDP + bo]);
            dv[0] = w0;
            dv[1] = w1;
        }
        __syncthreads();

        short8 a = *reinterpret_cast<const short8*>(&As[(wave * 16 + lr) * LDP + kg * 8]);
#pragma unroll
        for (int t = 0; t < 8; t++) {
            short8 b = *reinterpret_cast<const short8*>(&Bs[(t * 16 + lr) * LDP + kg * 8]);
            acc[t] = __builtin_amdgcn_mfma_f32_16x16x32_bf16(a, b, acc[t], 0, 0, 0);
        }
        __syncthreads();
    }

    int myrow0 = row0 + wave * 16 + kg * 4;
#pragma unroll
    for (int r = 0; r < 4; r++) {
        int row = myrow0 + r;
        if (row < n) {
#pragma unroll
            for (int t = 0; t < 8; t++) {
                h[(size_t)row * N_FEAT + t * 16 + lr] = acc[t][r];
            }
        }
    }
}

// ---------------------------------------------------------------------------
// aggregate: one wave per node. acc = h[v]*dinv[v]^2 + sum_e h[src]*dinv[src]*dinv[v]
// then + bias, log_softmax, single write of the output row. float2 per lane.
__global__ __launch_bounds__(256) void k_agg(const int* __restrict__ rowstart,
                                             const int* __restrict__ col,
                                             const float* __restrict__ dinv,
                                             const float* __restrict__ h,
                                             const float* __restrict__ bias,
                                             float* __restrict__ out, int n) {
    int wid = threadIdx.x >> 6, lane = threadIdx.x & 63;
    int v = blockIdx.x * 4 + wid;
    if (v >= n) return;
    float dv = dinv[v];
    const float2* hv = reinterpret_cast<const float2*>(h + (size_t)v * N_FEAT);
    float2 hself = hv[lane];
    float a0 = hself.x * dv * dv;
    float a1 = hself.y * dv * dv;

    int s = rowstart[v], epd = rowstart[v + 1];
    for (int e = s; e < epd; e++) {
        int src = col[e];                    // wave-uniform (broadcast)
        float w = dinv[src] * dv;
        const float2* hp = reinterpret_cast<const float2*>(h + (size_t)src * N_FEAT);
        float2 hx = hp[lane];
        a0 += hx.x * w;
        a1 += hx.y * w;
    }
    const float2* bp = reinterpret_cast<const float2*>(bias);
    float2 bb = bp[lane];
    a0 += bb.x;
    a1 += bb.y;

    float m = fmaxf(a0, a1);
#pragma unroll
    for (int sh = 32; sh; sh >>= 1) m = fmaxf(m, __shfl_xor(m, sh));
    float sum = __expf(a0 - m) + __expf(a1 - m);
#pragma unroll
    for (int sh = 32; sh; sh >>= 1) sum += __shfl_xor(sum, sh);
    float lse = m + __logf(sum);
    float2 o = make_float2(a0 - lse, a1 - lse);
    reinterpret_cast<float2*>(out + (size_t)v * N_FEAT)[lane] = o;
}

// ---------------------------------------------------------------------------
extern "C" void kernel_launch(void* const* d_in, const int* in_sizes, int n_in,
                              void* d_out, int out_size, void* d_ws, size_t ws_size,
                              hipStream_t stream) {
    const float* x = (const float*)d_in[0];
    const void* eidx = d_in[1];
    const float* W = (const float*)d_in[2];
    const float* b = (const float*)d_in[3];
    int n = in_sizes[0] / K_DIM;   // 50000
    int E = in_sizes[1] / 2;       // 800000
    float* out = (float*)d_out;

    char* ws = (char*)d_ws;
    int* flagp = (int*)ws;                        // @0
    int* cnt = (int*)(ws + 4096);                 // n int
    int* rowstart = (int*)(ws + 212992);          // n+1 int
    int* cursor = (int*)(ws + 417792);            // n int
    float* dinv = (float*)(ws + 622592);          // n f32
    short* Wt = (short*)(ws + 827392);            // 128*512 bf16
    int* col = (int*)(ws + 962560);               // E int = 3.2MB
    float* h = (float*)(ws + 4194304);            // n*128 f32 = 25.6MB

    k_detect<<<1, 512, 0, stream>>>((const long long*)eidx, (long long)n, flagp);
    k_wt<<<(K_DIM * N_FEAT) / 256, 256, 0, stream>>>(W, Wt);
    k_zero<<<(n + 255) / 256, 256, 0, stream>>>(cnt, n);
    k_hist<<<(E + 255) / 256, 256, 0, stream>>>(eidx, flagp, E, cnt);
    k_scan<<<1, 1024, 0, stream>>>(cnt, rowstart, cursor, dinv, n);
    k_gemm<<<(n + BM - 1) / BM, 256, 0, stream>>>(x, Wt, h, n);
    k_fill<<<(E + 255) / 256, 256, 0, stream>>>(eidx, flagp, E, cursor, col);
    k_agg<<<(n + 3) / 4, 256, 0, stream>>>(rowstart, col, dinv, h, b, out, n);
}

// Round 6
// 306.494 us; speedup vs baseline: 5.1749x; 1.3370x over previous
//
#include <hip/hip_runtime.h>
#include <hip/hip_bf16.h>

#define N_FEAT 128
#define K_DIM 512

typedef __attribute__((ext_vector_type(8))) short short8;
typedef __attribute__((ext_vector_type(4))) float f32x4;

static __device__ __forceinline__ short f2bf(float f) {
    // round-to-nearest-even f32 -> bf16
    unsigned u = __float_as_uint(f);
    unsigned r = (u + 0x7FFFu + ((u >> 16) & 1u)) >> 16;
    return (short)r;
}

static __device__ __forceinline__ float2 bfp(unsigned u) {
    // unpack 2 bf16 (packed little-endian) -> 2 f32
    return make_float2(__uint_as_float(u << 16), __uint_as_float(u & 0xFFFF0000u));
}

static __device__ __forceinline__ int load_idx(const void* e, int i, int is64) {
    return is64 ? (int)((const long long*)e)[i] : ((const int*)e)[i];
}

// ---------------------------------------------------------------------------
// setup: Wt transpose+bf16, zero cnt, detect index dtype (block 0)
__global__ __launch_bounds__(256) void k_setup(const float* __restrict__ W,
                                               short* __restrict__ Wt,
                                               int* __restrict__ cnt, int n,
                                               const long long* __restrict__ e,
                                               long long nmax, int* __restrict__ flag) {
    __shared__ int ok;
    int i = blockIdx.x * 256 + threadIdx.x;
    if (i < K_DIM * N_FEAT) {
        int k = i >> 7, c = i & 127;
        Wt[c * K_DIM + k] = f2bf(W[i]);
    }
    if (i < n) cnt[i] = 0;
    if (blockIdx.x == 0) {
        if (threadIdx.x == 0) ok = 1;
        __syncthreads();
        long long val = e[threadIdx.x];
        if (val < 0 || val >= nmax) ok = 0;  // benign race
        __syncthreads();
        if (threadIdx.x == 0) *flag = ok;
    }
}

// histogram of dst (self-loop +1 applied in dinv only)
__global__ void k_hist(const void* __restrict__ eidx, const int* __restrict__ flagp,
                       int E, int* __restrict__ cnt) {
    int i = blockIdx.x * 256 + threadIdx.x;
    if (i >= E) return;
    int is64 = *flagp;
    int dst = load_idx(eidx, E + i, is64);
    atomicAdd(&cnt[dst], 1);
}

// ---------------------------------------------------------------------------
// hierarchical exclusive scan (3 kernels); scan1 also computes dinv
__global__ __launch_bounds__(256) void k_scan1(const int* __restrict__ cnt,
                                               int* __restrict__ rowstart,
                                               int* __restrict__ btot,
                                               float* __restrict__ dinv, int n) {
    __shared__ int wtot[4];
    int tid = threadIdx.x, wid = tid >> 6, lane = tid & 63;
    int i = blockIdx.x * 256 + tid;
    int v = (i < n) ? cnt[i] : 0;
    if (i < n) dinv[i] = rsqrtf(1.0f + (float)v);
    int x = v;
#pragma unroll
    for (int off = 1; off < 64; off <<= 1) {
        int t = __shfl_up(x, off);
        if (lane >= off) x += t;
    }
    if (lane == 63) wtot[wid] = x;
    __syncthreads();
    if (tid == 0) {
        int a = wtot[0], b = wtot[1], c = wtot[2], d = wtot[3];
        wtot[0] = 0; wtot[1] = a; wtot[2] = a + b; wtot[3] = a + b + c;
        btot[blockIdx.x] = a + b + c + d;
    }
    __syncthreads();
    if (i < n) rowstart[i] = wtot[wid] + x - v;
}

__global__ __launch_bounds__(256) void k_scan2(const int* __restrict__ btot,
                                               int* __restrict__ boff,
                                               int* __restrict__ rowstart, int nb, int n) {
    __shared__ int wtot[4];
    int tid = threadIdx.x, wid = tid >> 6, lane = tid & 63;
    int v = (tid < nb) ? btot[tid] : 0;
    int x = v;
#pragma unroll
    for (int off = 1; off < 64; off <<= 1) {
        int t = __shfl_up(x, off);
        if (lane >= off) x += t;
    }
    if (lane == 63) wtot[wid] = x;
    __syncthreads();
    if (tid == 0) {
        int a = wtot[0], b = wtot[1], c = wtot[2];
        wtot[0] = 0; wtot[1] = a; wtot[2] = a + b; wtot[3] = a + b + c;
    }
    __syncthreads();
    int excl = wtot[wid] + x - v;
    if (tid < nb) boff[tid] = excl;
    if (tid == nb - 1) rowstart[n] = excl + v;
}

__global__ void k_scan3(int* __restrict__ rowstart, int* __restrict__ cursor,
                        const int* __restrict__ boff, int n) {
    int i = blockIdx.x * 256 + threadIdx.x;
    if (i < n) {
        int r = rowstart[i] + boff[blockIdx.x];
        rowstart[i] = r;
        cursor[i] = r;
    }
}

// scatter edge ids into CSR slots (int atomics on 200KB cursor array only)
__global__ void k_fill(const void* __restrict__ eidx, const int* __restrict__ flagp,
                       int E, int* __restrict__ cursor, int* __restrict__ col) {
    int e = blockIdx.x * 256 + threadIdx.x;
    if (e >= E) return;
    int is64 = *flagp;
    int src = load_idx(eidx, e, is64);
    int dst = load_idx(eidx, E + e, is64);
    int slot = atomicAdd(&cursor[dst], 1);
    col[slot] = src;
}

// ---------------------------------------------------------------------------
// h = x @ W via bf16 MFMA; h written as bf16 (ushort)
#define BM 64
#define BK 32
#define LDP 40  // padded LDS stride (bf16 elems)

__global__ __launch_bounds__(256) void k_gemm(const float* __restrict__ x,
                                              const short* __restrict__ Wt,
                                              unsigned short* __restrict__ h, int n) {
    __shared__ __align__(16) short As[BM * LDP];
    __shared__ __align__(16) short Bs[N_FEAT * LDP];
    int tid = threadIdx.x;
    int wave = tid >> 6, lane = tid & 63;
    int lr = lane & 15, kg = lane >> 4;
    int row0 = blockIdx.x * BM;

    f32x4 acc[8];
#pragma unroll
    for (int t = 0; t < 8; t++) acc[t] = (f32x4)(0.0f);

    int arow = tid >> 2;
    int aq = (tid & 3) * 8;
    int bcol = tid >> 1;
    int bo = (tid & 1) * 16;

    for (int k0 = 0; k0 < K_DIM; k0 += BK) {
        {
            int grow = row0 + arow;
            float4 v0, v1;
            if (grow < n) {
                const float4* p =
                    reinterpret_cast<const float4*>(x + (size_t)grow * K_DIM + k0 + aq);
                v0 = p[0];
                v1 = p[1];
            } else {
                v0 = make_float4(0, 0, 0, 0);
                v1 = v0;
            }
            short* d = &As[arow * LDP + aq];
            d[0] = f2bf(v0.x); d[1] = f2bf(v0.y); d[2] = f2bf(v0.z); d[3] = f2bf(v0.w);
            d[4] = f2bf(v1.x); d[5] = f2bf(v1.y); d[6] = f2bf(v1.z); d[7] = f2bf(v1.w);
        }
        {
            const float4* pv =
                reinterpret_cast<const float4*>(Wt + bcol * K_DIM + k0 + bo);
            float4 w0 = pv[0];
            float4 w1 = pv[1];
            float4* dv = reinterpret_cast<float4*>(&Bs[bcol * LDP + bo]);
            dv[0] = w0;
            dv[1] = w1;
        }
        __syncthreads();

        short8 a = *reinterpret_cast<const short8*>(&As[(wave * 16 + lr) * LDP + kg * 8]);
#pragma unroll
        for (int t = 0; t < 8; t++) {
            short8 b = *reinterpret_cast<const short8*>(&Bs[(t * 16 + lr) * LDP + kg * 8]);
            acc[t] = __builtin_amdgcn_mfma_f32_16x16x32_bf16(a, b, acc[t], 0, 0, 0);
        }
        __syncthreads();
    }

    int myrow0 = row0 + wave * 16 + kg * 4;
#pragma unroll
    for (int r = 0; r < 4; r++) {
        int row = myrow0 + r;
        if (row < n) {
#pragma unroll
            for (int t = 0; t < 8; t++) {
                h[(size_t)row * N_FEAT + t * 16 + lr] = (unsigned short)f2bf(acc[t][r]);
            }
        }
    }
}

// ---------------------------------------------------------------------------
// aggregate (bf16 h, unroll-4 gathers) + bias + log_softmax, one wave/node
__global__ __launch_bounds__(256) void k_agg(const int* __restrict__ rowstart,
                                             const int* __restrict__ col,
                                             const float* __restrict__ dinv,
                                             const unsigned* __restrict__ h,
                                             const float* __restrict__ bias,
                                             float* __restrict__ out, int n) {
    int wid = threadIdx.x >> 6, lane = threadIdx.x & 63;
    int v = blockIdx.x * 4 + wid;
    if (v >= n) return;
    float dv = dinv[v];
    float2 hself = bfp(h[(size_t)v * 64 + lane]);
    float sl = dv * dv;
    float a0 = hself.x * sl;
    float a1 = hself.y * sl;

    int e = rowstart[v], eend = rowstart[v + 1];
    for (; e + 4 <= eend; e += 4) {
        int s0 = col[e], s1 = col[e + 1], s2 = col[e + 2], s3 = col[e + 3];
        float w0 = dinv[s0], w1 = dinv[s1], w2 = dinv[s2], w3 = dinv[s3];
        unsigned g0 = h[(size_t)s0 * 64 + lane];
        unsigned g1 = h[(size_t)s1 * 64 + lane];
        unsigned g2 = h[(size_t)s2 * 64 + lane];
        unsigned g3 = h[(size_t)s3 * 64 + lane];
        w0 *= dv; w1 *= dv; w2 *= dv; w3 *= dv;
        float2 f0 = bfp(g0), f1 = bfp(g1), f2 = bfp(g2), f3 = bfp(g3);
        a0 += f0.x * w0; a1 += f0.y * w0;
        a0 += f1.x * w1; a1 += f1.y * w1;
        a0 += f2.x * w2; a1 += f2.y * w2;
        a0 += f3.x * w3; a1 += f3.y * w3;
    }
    for (; e < eend; e++) {
        int s0 = col[e];
        float w = dinv[s0] * dv;
        float2 f = bfp(h[(size_t)s0 * 64 + lane]);
        a0 += f.x * w;
        a1 += f.y * w;
    }
    float2 bb = reinterpret_cast<const float2*>(bias)[lane];
    a0 += bb.x;
    a1 += bb.y;

    float m = fmaxf(a0, a1);
#pragma unroll
    for (int sh = 32; sh; sh >>= 1) m = fmaxf(m, __shfl_xor(m, sh));
    float sum = __expf(a0 - m) + __expf(a1 - m);
#pragma unroll
    for (int sh = 32; sh; sh >>= 1) sum += __shfl_xor(sum, sh);
    float lse = m + __logf(sum);
    reinterpret_cast<float2*>(out + (size_t)v * N_FEAT)[lane] =
        make_float2(a0 - lse, a1 - lse);
}

// ---------------------------------------------------------------------------
extern "C" void kernel_launch(void* const* d_in, const int* in_sizes, int n_in,
                              void* d_out, int out_size, void* d_ws, size_t ws_size,
                              hipStream_t stream) {
    const float* x = (const float*)d_in[0];
    const void* eidx = d_in[1];
    const float* W = (const float*)d_in[2];
    const float* b = (const float*)d_in[3];
    int n = in_sizes[0] / K_DIM;   // 50000
    int E = in_sizes[1] / 2;       // 800000
    float* out = (float*)d_out;

    char* ws = (char*)d_ws;
    int* flagp = (int*)ws;                        // @0
    int* btot = (int*)(ws + 256);                 // 256 ints
    int* boff = (int*)(ws + 2048);                // 256 ints
    int* cnt = (int*)(ws + 8192);                 // n ints
    int* rowstart = (int*)(ws + 212992);          // n+1 ints
    int* cursor = (int*)(ws + 417792);            // n ints
    float* dinv = (float*)(ws + 622592);          // n f32
    short* Wt = (short*)(ws + 827392);            // 128*512 bf16
    int* col = (int*)(ws + 962560);               // E ints = 3.2MB
    unsigned short* h = (unsigned short*)(ws + 4194304);  // n*128 bf16 = 12.8MB

    int nbN = (n + 255) / 256;                    // 196
    int nbS = nbN > 256 ? nbN : 256;              // covers 65536 Wt elems too

    k_setup<<<nbS, 256, 0, stream>>>(W, Wt, cnt, n, (const long long*)eidx,
                                     (long long)n, flagp);
    k_hist<<<(E + 255) / 256, 256, 0, stream>>>(eidx, flagp, E, cnt);
    k_scan1<<<nbN, 256, 0, stream>>>(cnt, rowstart, btot, dinv, n);
    k_scan2<<<1, 256, 0, stream>>>(btot, boff, rowstart, nbN, n);
    k_scan3<<<nbN, 256, 0, stream>>>(rowstart, cursor, boff, n);
    k_fill<<<(E + 255) / 256, 256, 0, stream>>>(eidx, flagp, E, cursor, col);
    k_gemm<<<(n + BM - 1) / BM, 256, 0, stream>>>(x, Wt, h, n);
    k_agg<<<(n + 3) / 4, 256, 0, stream>>>(rowstart, col, dinv,
                                           reinterpret_cast<const unsigned*>(h), b, out, n);
}